// Round 19
// baseline (105.002 us; speedup 1.0000x reference)
//
#include <hip/hip_runtime.h>

#define B_ 128
#define NPG 512
#define EPG 2048
#define NREL 114
#define XS 18   // row stride (floats); slots 0..15 = x, slot 16 = dead-logit-penalty

// monotone float->uint key (total order matching float compare, no NaNs here)
__device__ __forceinline__ unsigned fkey(float f){
  unsigned u = __float_as_uint(f);
  return (u & 0x80000000u) ? ~u : (u | 0x80000000u);
}
__device__ __forceinline__ float fdec(unsigned k){
  return (k & 0x80000000u) ? __uint_as_float(k & 0x7FFFFFFFu) : __uint_as_float(~k);
}
__device__ __forceinline__ float dot4f(float4 a, float4 b){
  return a.x*b.x + a.y*b.y + a.z*b.z + a.w*b.w;
}

// block-wide: exclusive scan of s_hist[0..512) -> s_off[1..512] inclusive ends,
// s_off[0]=0, s_hist[bin] = exclusive start (running scatter counter).
// Contains 2 internal barriers; caller must barrier after.
__device__ __forceinline__ void scan512(int* s_hist, int* s_off, int* s_wt, int tid){
  int lane = tid & 63, wv = tid >> 6;
  int cnt = 0, inc = 0;
  if (wv < 8){
    cnt = s_hist[wv*64 + lane];
    inc = cnt;
    #pragma unroll
    for (int o=1; o<64; o<<=1){ int t=__shfl_up(inc,o); if (lane>=o) inc += t; }
    if (lane==63) s_wt[wv] = inc;
  }
  __syncthreads();
  if (tid < 8){
    int e = 0;
    #pragma unroll
    for (int j=0;j<8;j++) if (j<tid) e += s_wt[j];
    s_wt[8+tid] = e;
  }
  __syncthreads();
  if (wv < 8){
    int base = s_wt[8+wv];
    s_off[wv*64+lane+1] = base + inc;
    s_hist[wv*64+lane]  = base + inc - cnt;
  }
  if (tid==0) s_off[0] = 0;
}

// One block per graph, LDS-resident, 1 launch. STATIC CSR-by-dst (built once);
// whole RGAT layer per-node in registers (4-lane group per node), degree-sorted
// A/B pairing, online-softmax fused sweep, dead-node logit penalty (no per-layer
// compaction). Single delta vs R18: Wq/Wk for ALL 3 layers precomputed in init
// (s_wq3/s_wk3, +36.5 KB LDS) -- deletes 2 A-phases + 4 barriers per block;
// the layer loop is now pure PM -> feats -> top-k.
__global__ __launch_bounds__(1024, 4) void k_fused(
    const float* __restrict__ emb, const float* __restrict__ gnn_w,
    const float* __restrict__ gnn_q, const float* __restrict__ gnn_k,
    const float* __restrict__ gnn_b, const float* __restrict__ pool_w,
    const float* __restrict__ w1, const float* __restrict__ b1,
    const float* __restrict__ w2, const float* __restrict__ b2,
    const float* __restrict__ w3, const float* __restrict__ b3,
    const int* __restrict__ xattr, const int* __restrict__ src,
    const int* __restrict__ dst, const int* __restrict__ et,
    float* __restrict__ out)
{
  __shared__ float s_x[NPG*XS];            // 36864 B (slot 16 = penalty)
  __shared__ float s_wq3[3*NREL*XS];       // 24624 B (all 3 layers)
  __shared__ float s_wk3[3*NREL*XS];       // 24624 B
  __shared__ unsigned s_epk[EPG+2];        // 8200 B: src | (type<<16); +2 prefetch pad
  __shared__ int s_off[NPG+1];
  __shared__ int s_hist[NPG];
  __shared__ unsigned s_keys[NPG];
  __shared__ int s_mask[NPG];
  __shared__ unsigned short s_perm[NPG];   // degree-sorted node order (static)
  __shared__ int s_dh[64];                 // degree histogram (cap 63)
  __shared__ int s_wt[16];
  __shared__ float s_sum[16];
  __shared__ unsigned s_max16[16];
  __shared__ int s_w[16];
  __shared__ float s_feats[96];
  __shared__ float s_h1[16], s_h2[4];

  const int b = blockIdx.x, tid = threadIdx.x;
  const int lane = tid & 63, wv = tid >> 6;
  const int og = tid & 3, grp = tid >> 2;    // 256 node-groups of 4 lanes
  const int nb = b*NPG;
  const size_t gb = (size_t)b*EPG;

  // ---- init: emb gather + Wq/Wk for ALL layers + STATIC CSR + degree perm
  if (tid < NPG){
    int a = xattr[nb + tid];
    const float2* e2 = (const float2*)(emb + a*16);
    #pragma unroll
    for (int c=0;c<8;c++) *(float2*)&s_x[tid*XS + 2*c] = e2[c];
    s_x[tid*XS+16] = 0.f;    // alive: zero logit penalty
    s_x[tid*XS+17] = 0.f;
    s_mask[tid] = 1;
  }
  for (int i=tid;i<NPG;i+=1024) s_hist[i]=0;
  if (tid<64) s_dh[tid]=0;
  if (tid<2) s_epk[EPG+tid]=0;
  __syncthreads();
  for (int e=tid;e<EPG;e+=1024) atomicAdd(&s_hist[dst[gb+e]-nb], 1);
  // Wq/Wk all 3 layers: item i = l*1824 + rd; W row at gnn_w + i*16
  for (int i=tid; i<3*NREL*16; i+=1024){
    int l = i / (NREL*16);
    int rd = i - l*(NREL*16);
    const float4* wr = (const float4*)(gnn_w + (size_t)i*16);
    float4 a0=wr[0],a1=wr[1],a2=wr[2],a3=wr[3];
    const float4* q4 = (const float4*)(gnn_q + l*16);
    const float4* k4 = (const float4*)(gnn_k + l*16);
    int idx = l*(NREL*XS) + (rd>>4)*XS + (rd&15);
    s_wq3[idx] = dot4f(a0,q4[0])+dot4f(a1,q4[1])+dot4f(a2,q4[2])+dot4f(a3,q4[3]);
    s_wk3[idx] = dot4f(a0,k4[0])+dot4f(a1,k4[1])+dot4f(a2,k4[2])+dot4f(a3,k4[3]);
  }
  __syncthreads();
  scan512(s_hist, s_off, s_wt, tid);
  __syncthreads();
  {
    for (int e=tid;e<EPG;e+=1024){
      int d = dst[gb+e]-nb;
      int p = atomicAdd(&s_hist[d], 1);
      s_epk[p] = (unsigned)(src[gb+e]-nb) | ((unsigned)et[gb+e]<<16);
    }
    int mydeg = 0;
    if (tid<NPG){
      mydeg = s_off[tid+1]-s_off[tid]; if (mydeg>63) mydeg=63;
      atomicAdd(&s_dh[mydeg], 1);
    }
    __syncthreads();
    if (tid<64){
      int c = s_dh[tid], inc = c;
      #pragma unroll
      for (int o=1;o<64;o<<=1){ int t=__shfl_up(inc,o); if (tid>=o) inc+=t; }
      s_dh[tid] = inc - c;
    }
    __syncthreads();
    if (tid<NPG){ int p = atomicAdd(&s_dh[mydeg],1); s_perm[p]=(unsigned short)tid; }
  }
  __syncthreads();

  const int cnts[3] = {512, 410, 328};   // static alive counts
  const int kks[2]  = {410, 328};        // ceil(0.8*512), ceil(0.8*410)

  for (int l=0; l<3; ++l){
    const float* Wl  = gnn_w + (size_t)l*NREL*256;
    const float* wqL = s_wq3 + l*(NREL*XS);
    const float* wkL = s_wk3 + l*(NREL*XS);
    if (tid<16){ s_sum[tid]=0.f; s_max16[tid]=0u; }
    __syncthreads();
    // ---- PM: per-node merged logit/softmax/aggregate/norm/pool/score
    float rnorm=0.f; float pw4[4]={0,0,0,0};
    if (l<2){
      float ss=0.f;
      #pragma unroll
      for (int o=0;o<16;o++){ float p=pool_w[l*16+o]; ss+=p*p; }
      rnorm = rsqrtf(ss);
      #pragma unroll
      for (int j=0;j<4;j++) pw4[j]=pool_w[l*16+4*og+j];
    }
    const float* bb = gnn_b + l*16;
    const int nA = s_perm[grp], nB = s_perm[511-grp];
    float zA[4], zB[4];
    auto pm_round = [&](int n, float* z){
      int beg = s_off[n], end = s_off[n+1];
      int alive = s_mask[n];
      float2 xt0 = *(const float2*)&s_x[n*XS+4*og];
      float2 xt1 = *(const float2*)&s_x[n*XS+4*og+2];
      // fused sweep: logits + online softmax + W-gather accumulate, 2-edge
      // unroll, epk pair software-pipelined (prefetched one iter ahead)
      float m = -1e30f;
      float den=0.f, v0=0.f, v1=0.f, v2=0.f, v3=0.f;
      int p = beg;
      unsigned pkA = 0u, pkB = 0u;
      if (p+2 <= end){ pkA = s_epk[p]; pkB = s_epk[p+1]; }
      for (; p+2 <= end; p += 2){
        unsigned pk0 = pkA, pk1 = pkB;
        pkA = s_epk[p+2]; pkB = s_epk[p+3];   // prefetch next iter (padded)
        int s0 = pk0 & 0xFFFF, r0 = pk0 >> 16;
        int s1 = pk1 & 0xFFFF, r1 = pk1 >> 16;
        float pen0 = s_x[s0*XS+16];           // dead src -> -1e30
        float pen1 = s_x[s1*XS+16];
        // logits (4-way split dot + 2 shfl each)
        float2 wq00=*(const float2*)&wqL[r0*XS+4*og];
        float2 wq01=*(const float2*)&wqL[r0*XS+4*og+2];
        float2 wk00=*(const float2*)&wkL[r0*XS+4*og];
        float2 wk01=*(const float2*)&wkL[r0*XS+4*og+2];
        float2 xs00=*(const float2*)&s_x[s0*XS+4*og];
        float2 xs01=*(const float2*)&s_x[s0*XS+4*og+2];
        float a0 = xt0.x*wq00.x + xt0.y*wq00.y + xt1.x*wq01.x + xt1.y*wq01.y
                 + xs00.x*wk00.x + xs00.y*wk00.y + xs01.x*wk01.x + xs01.y*wk01.y;
        float2 wq10=*(const float2*)&wqL[r1*XS+4*og];
        float2 wq11=*(const float2*)&wqL[r1*XS+4*og+2];
        float2 wk10=*(const float2*)&wkL[r1*XS+4*og];
        float2 wk11=*(const float2*)&wkL[r1*XS+4*og+2];
        float2 xs10=*(const float2*)&s_x[s1*XS+4*og];
        float2 xs11=*(const float2*)&s_x[s1*XS+4*og+2];
        float a1 = xt0.x*wq10.x + xt0.y*wq10.y + xt1.x*wq11.x + xt1.y*wq11.y
                 + xs10.x*wk10.x + xs10.y*wk10.y + xs11.x*wk11.x + xs11.y*wk11.y;
        a0 += __shfl_xor(a0,1); a0 += __shfl_xor(a0,2);
        a1 += __shfl_xor(a1,1); a1 += __shfl_xor(a1,2);
        float lg0 = (a0>0.f ? a0 : 0.2f*a0) + pen0;   // leaky_relu 0.2 + dead penalty
        float lg1 = (a1>0.f ? a1 : 0.2f*a1) + pen1;
        // W gather (independent load chains, overlap the logit shfl chain)
        const float4* wr0 = (const float4*)(Wl + (size_t)r0*256) + og;
        const float4* wr1 = (const float4*)(Wl + (size_t)r1*256) + og;
        const float* xr0 = &s_x[s0*XS];
        const float* xr1 = &s_x[s1*XS];
        float h00=0.f,h01=0.f,h02=0.f,h03=0.f;
        float h10=0.f,h11=0.f,h12=0.f,h13=0.f;
        #pragma unroll
        for (int d2=0; d2<8; ++d2){
          float2 xa = *(const float2*)&xr0[2*d2];
          float2 xb = *(const float2*)&xr1[2*d2];
          float4 wA0 = wr0[(2*d2)*4], wB0 = wr0[(2*d2+1)*4];
          float4 wA1 = wr1[(2*d2)*4], wB1 = wr1[(2*d2+1)*4];
          h00 += xa.x*wA0.x + xa.y*wB0.x;  h01 += xa.x*wA0.y + xa.y*wB0.y;
          h02 += xa.x*wA0.z + xa.y*wB0.z;  h03 += xa.x*wA0.w + xa.y*wB0.w;
          h10 += xb.x*wA1.x + xb.y*wB1.x;  h11 += xb.x*wA1.y + xb.y*wB1.y;
          h12 += xb.x*wA1.z + xb.y*wB1.z;  h13 += xb.x*wA1.w + xb.y*wB1.w;
        }
        // online softmax update (dead edges: e=0 once any live max seen;
        // their h is 0 anyway since dead x rows are zeroed)
        float nm = fmaxf(m, fmaxf(lg0, lg1));
        float sc = __expf(m - nm);             // m=-1e30 first iter -> sc=0
        float e0 = __expf(lg0 - nm);
        float e1 = __expf(lg1 - nm);
        den = den*sc + e0 + e1;
        v0 = v0*sc + e0*h00 + e1*h10;
        v1 = v1*sc + e0*h01 + e1*h11;
        v2 = v2*sc + e0*h02 + e1*h12;
        v3 = v3*sc + e0*h03 + e1*h13;
        m = nm;
      }
      if (p < end){
        unsigned pk = s_epk[p];
        int s = pk & 0xFFFF, r = pk >> 16;
        float pen = s_x[s*XS+16];
        float2 wq0=*(const float2*)&wqL[r*XS+4*og];
        float2 wq1=*(const float2*)&wqL[r*XS+4*og+2];
        float2 wk0=*(const float2*)&wkL[r*XS+4*og];
        float2 wk1=*(const float2*)&wkL[r*XS+4*og+2];
        float2 xs0=*(const float2*)&s_x[s*XS+4*og];
        float2 xs1=*(const float2*)&s_x[s*XS+4*og+2];
        float a = xt0.x*wq0.x + xt0.y*wq0.y + xt1.x*wq1.x + xt1.y*wq1.y
                + xs0.x*wk0.x + xs0.y*wk0.y + xs1.x*wk1.x + xs1.y*wk1.y;
        a += __shfl_xor(a,1); a += __shfl_xor(a,2);
        float lg = (a>0.f ? a : 0.2f*a) + pen;
        const float4* wr = (const float4*)(Wl + (size_t)r*256) + og;
        const float* xr = &s_x[s*XS];
        float h0=0.f,h1=0.f,h2=0.f,h3=0.f;
        #pragma unroll
        for (int d2=0; d2<8; ++d2){
          float2 xs2 = *(const float2*)&xr[2*d2];
          float4 wA = wr[(2*d2)*4];
          float4 wB = wr[(2*d2+1)*4];
          h0 += xs2.x*wA.x + xs2.y*wB.x;
          h1 += xs2.x*wA.y + xs2.y*wB.y;
          h2 += xs2.x*wA.z + xs2.y*wB.z;
          h3 += xs2.x*wA.w + xs2.y*wB.w;
        }
        float nm = fmaxf(m, lg);
        float sc = __expf(m - nm);
        float ex = __expf(lg - nm);
        den = den*sc + ex;
        v0 = v0*sc + ex*h0;
        v1 = v1*sc + ex*h1;
        v2 = v2*sc + ex*h2;
        v3 = v3*sc + ex*h3;
        m = nm;
      }
      float inv = den>0.f ? 1.f/den : 1.f;   // ref: where(den>0, den, 1)
      z[0]=v0*inv+bb[4*og+0]; z[1]=v1*inv+bb[4*og+1];
      z[2]=v2*inv+bb[4*og+2]; z[3]=v3*inv+bb[4*og+3];
      #pragma unroll
      for (int j=0;j<4;j++){ if (z[j]<0.f) z[j]=0.f; }
      if (!alive){ z[0]=z[1]=z[2]=z[3]=0.f; }
      // pool partials: reduce across the wave's 16 node-groups (4-hop shfl)
      #pragma unroll
      for (int j=0;j<4;j++){
        float sv=z[j], mv=z[j];
        #pragma unroll
        for (int off=4; off<64; off<<=1){
          sv += __shfl_xor(sv, off);
          mv = fmaxf(mv, __shfl_xor(mv, off));
        }
        if ((lane>>2)==0){
          atomicAdd(&s_sum[4*og+j], sv);
          atomicMax(&s_max16[4*og+j], __float_as_uint(mv));
        }
      }
      if (l<2){
        float dq = z[0]*pw4[0]+z[1]*pw4[1]+z[2]*pw4[2]+z[3]*pw4[3];
        dq += __shfl_xor(dq,1); dq += __shfl_xor(dq,2);
        if (og==0){
          float sc2 = tanhf(dq*rnorm);
          s_keys[n] = alive ? fkey(sc2) : 0u;   // dead -> 0; alive keys > 0
        }
      }
    };
    pm_round(nA, zA);
    pm_round(nB, zB);
    __syncthreads();
    if (tid<16){
      s_feats[l*32+tid]    = s_sum[tid]/(float)cnts[l];
      s_feats[l*32+16+tid] = __uint_as_float(s_max16[tid]);
    }
    if (l==2) break;
    // ---- z writeback (deferred past barrier: WAR vs fused-sweep x_s reads)
    {
      *(float2*)&s_x[nA*XS+4*og]   = make_float2(zA[0],zA[1]);
      *(float2*)&s_x[nA*XS+4*og+2] = make_float2(zA[2],zA[3]);
      *(float2*)&s_x[nB*XS+4*og]   = make_float2(zB[0],zB[1]);
      *(float2*)&s_x[nB*XS+4*og+2] = make_float2(zB[2],zB[3]);
    }
    __syncthreads();
    // ---- top-k: register-resident wave-redundant bitwise search
    {
      const int kk = kks[l];
      unsigned kreg[8];
      #pragma unroll
      for (int j=0;j<8;j++) kreg[j] = s_keys[lane + j*64];
      unsigned cur = 0u;
      for (int bit=31; bit>=0; --bit){
        unsigned cand = cur | (1u<<bit);
        int c=0;
        #pragma unroll
        for (int j=0;j<8;j++) c += __popcll(__ballot(kreg[j]>=cand));
        if (c >= kk) cur = cand;
      }
      int cgt=0;
      #pragma unroll
      for (int j=0;j<8;j++) cgt += __popcll(__ballot(kreg[j]>cur));
      int ties = kk - cgt;
      // rank among equals by node index (jax top_k lowest-index tie-break)
      unsigned myk = (tid<NPG) ? s_keys[tid] : 0u;
      bool eq = (tid<NPG) && (myk==cur);
      unsigned long long bal = __ballot(eq);
      int lrank = __popcll(bal & ((1ull<<lane)-1ull));
      if (lane==0) s_w[wv] = __popcll(bal);
      __syncthreads();
      int pre=0;
      #pragma unroll
      for (int w=0; w<16; ++w) if (w<wv) pre += s_w[w];
      int rank = pre + lrank;
      if (tid < NPG){
        bool keep = (myk > cur) || (eq && rank < ties);
        float mult = keep ? fdec(myk) : 0.f;   // exact tanh-score roundtrip
        #pragma unroll
        for (int c=0;c<8;c++){
          float2 t2 = *(const float2*)&s_x[tid*XS+2*c];
          t2.x *= mult; t2.y *= mult;
          *(float2*)&s_x[tid*XS+2*c] = t2;
        }
        s_x[tid*XS+16] = keep ? 0.f : -1e30f;  // dead -> logit penalty
        s_mask[tid] = keep ? 1 : 0;
      }
    }
    __syncthreads();
    // (no edge compaction: CSR/perm static; dead edges neutralized by penalty)
  }

  // ---- MLP head (feats never leave LDS)
  __syncthreads();
  if (tid < 16){
    float a = b1[tid];
    for (int i=0;i<96;i++) a += s_feats[i]*w1[i*16+tid];
    s_h1[tid] = a>0.f?a:0.f;
  }
  __syncthreads();
  if (tid < 4){
    float a = b2[tid];
    #pragma unroll
    for (int i=0;i<16;i++) a += s_h1[i]*w2[i*4+tid];
    s_h2[tid] = a>0.f?a:0.f;
  }
  __syncthreads();
  if (tid == 0){
    float z = b3[0];
    #pragma unroll
    for (int i=0;i<4;i++) z += s_h2[i]*w3[i];
    out[b] = 1.f/(1.f+expf(-z));
  }
}

extern "C" void kernel_launch(void* const* d_in, const int* in_sizes, int n_in,
                              void* d_out, int out_size, void* d_ws, size_t ws_size,
                              hipStream_t stream) {
  const float* emb    = (const float*)d_in[0];
  const float* gnn_w  = (const float*)d_in[1];
  const float* gnn_q  = (const float*)d_in[2];
  const float* gnn_k  = (const float*)d_in[3];
  const float* gnn_b  = (const float*)d_in[4];
  const float* pool_w = (const float*)d_in[5];
  const float* w1 = (const float*)d_in[6];
  const float* b1 = (const float*)d_in[7];
  const float* w2 = (const float*)d_in[8];
  const float* b2 = (const float*)d_in[9];
  const float* w3 = (const float*)d_in[10];
  const float* b3 = (const float*)d_in[11];
  const int* xattr = (const int*)d_in[12];
  const int* eidx  = (const int*)d_in[13];
  const int* etype = (const int*)d_in[14];
  const int* src = eidx;
  const int* dst = eidx + (size_t)B_*EPG;

  k_fused<<<B_, 1024, 0, stream>>>(emb, gnn_w, gnn_q, gnn_k, gnn_b, pool_w,
                                   w1, b1, w2, b2, w3, b3,
                                   xattr, src, dst, etype, (float*)d_out);
}

// Round 20
// 100.042 us; speedup vs baseline: 1.0496x; 1.0496x over previous
//
#include <hip/hip_runtime.h>

#define B_ 128
#define NPG 512
#define EPG 2048
#define NREL 114
#define XS 18   // row stride (floats) for s_x/s_wq/s_wk: 72B, 8B-aligned float2 rows

// monotone float->uint key (total order matching float compare, no NaNs here)
__device__ __forceinline__ unsigned fkey(float f){
  unsigned u = __float_as_uint(f);
  return (u & 0x80000000u) ? ~u : (u | 0x80000000u);
}
__device__ __forceinline__ float fdec(unsigned k){
  return (k & 0x80000000u) ? __uint_as_float(k & 0x7FFFFFFFu) : __uint_as_float(~k);
}
__device__ __forceinline__ float dot4f(float4 a, float4 b){
  return a.x*b.x + a.y*b.y + a.z*b.z + a.w*b.w;
}

// block-wide: exclusive scan of s_hist[0..512) -> s_off[1..512] inclusive ends,
// s_off[0]=0, s_hist[bin] = exclusive start (running scatter counter).
// Contains 2 internal barriers; caller must barrier after.
__device__ __forceinline__ void scan512(int* s_hist, int* s_off, int* s_wt, int tid){
  int lane = tid & 63, wv = tid >> 6;
  int cnt = 0, inc = 0;
  if (wv < 8){
    cnt = s_hist[wv*64 + lane];
    inc = cnt;
    #pragma unroll
    for (int o=1; o<64; o<<=1){ int t=__shfl_up(inc,o); if (lane>=o) inc += t; }
    if (lane==63) s_wt[wv] = inc;
  }
  __syncthreads();
  if (tid < 8){
    int e = 0;
    #pragma unroll
    for (int j=0;j<8;j++) if (j<tid) e += s_wt[j];
    s_wt[8+tid] = e;
  }
  __syncthreads();
  if (wv < 8){
    int base = s_wt[8+wv];
    s_off[wv*64+lane+1] = base + inc;
    s_hist[wv*64+lane]  = base + inc - cnt;
  }
  if (tid==0) s_off[0] = 0;
}

// One block per graph, LDS-resident, 1 launch. CSR-by-dst; whole RGAT layer
// per-node in registers (4-lane group per node); degree-sorted A/B pairing.
// Online-softmax fused single sweep; packed edge metadata (src|type<<16, one
// dependent LDS read/edge); epk pair software-pipelined one iter ahead.
// [BEST RECORDED STATE: R17, 100.53 us -- reverted after R18/R19 levers
//  (compaction removal, Wq/Wk hoist) measured flat/negative.]
__global__ __launch_bounds__(1024, 4) void k_fused(
    const float* __restrict__ emb, const float* __restrict__ gnn_w,
    const float* __restrict__ gnn_q, const float* __restrict__ gnn_k,
    const float* __restrict__ gnn_b, const float* __restrict__ pool_w,
    const float* __restrict__ w1, const float* __restrict__ b1,
    const float* __restrict__ w2, const float* __restrict__ b2,
    const float* __restrict__ w3, const float* __restrict__ b3,
    const int* __restrict__ xattr, const int* __restrict__ src,
    const int* __restrict__ dst, const int* __restrict__ et,
    float* __restrict__ out)
{
  __shared__ float s_x[NPG*XS];            // 36864 B
  __shared__ float s_wq[NREL*XS];          // 8208 B
  __shared__ float s_wk[NREL*XS];          // 8208 B
  __shared__ unsigned s_epk[EPG+2];        // 8200 B: src | (type<<16); +2 prefetch pad
  __shared__ unsigned short s_edst[EPG];   // 4096 B: dst (binning/compaction only)
  __shared__ int s_off[NPG+1];
  __shared__ int s_hist[NPG];
  __shared__ unsigned s_keys[NPG];
  __shared__ int s_mask[NPG];
  __shared__ unsigned short s_perm[NPG];   // degree-sorted node order
  __shared__ int s_dh[64];                 // degree histogram (cap 63)
  __shared__ int s_wt[16];
  __shared__ float s_sum[16];
  __shared__ unsigned s_max16[16];
  __shared__ int s_w[16];
  __shared__ float s_feats[96];
  __shared__ float s_h1[16], s_h2[4];

  const int b = blockIdx.x, tid = threadIdx.x;
  const int lane = tid & 63, wv = tid >> 6;
  const int og = tid & 3, grp = tid >> 2;    // 256 node-groups of 4 lanes
  const int nb = b*NPG;
  const size_t gb = (size_t)b*EPG;

  // ---- init: emb gather + CSR-by-dst build
  if (tid < NPG){
    int a = xattr[nb + tid];
    const float2* e2 = (const float2*)(emb + a*16);
    #pragma unroll
    for (int c=0;c<8;c++) *(float2*)&s_x[tid*XS + 2*c] = e2[c];
    s_mask[tid] = 1;
  }
  for (int i=tid;i<NPG;i+=1024) s_hist[i]=0;
  if (tid<64) s_dh[tid]=0;
  if (tid<2) s_epk[EPG+tid]=0;
  __syncthreads();
  for (int e=tid;e<EPG;e+=1024) atomicAdd(&s_hist[dst[gb+e]-nb], 1);
  __syncthreads();
  scan512(s_hist, s_off, s_wt, tid);
  __syncthreads();
  {
    for (int e=tid;e<EPG;e+=1024){
      int d = dst[gb+e]-nb;
      int p = atomicAdd(&s_hist[d], 1);
      s_epk[p]  = (unsigned)(src[gb+e]-nb) | ((unsigned)et[gb+e]<<16);
      s_edst[p] = (unsigned short)d;
    }
    int mydeg = 0;
    if (tid<NPG){
      mydeg = s_off[tid+1]-s_off[tid]; if (mydeg>63) mydeg=63;
      atomicAdd(&s_dh[mydeg], 1);
    }
    __syncthreads();
    if (tid<64){
      int c = s_dh[tid], inc = c;
      #pragma unroll
      for (int o=1;o<64;o<<=1){ int t=__shfl_up(inc,o); if (tid>=o) inc+=t; }
      s_dh[tid] = inc - c;
    }
    __syncthreads();
    if (tid<NPG){ int p = atomicAdd(&s_dh[mydeg],1); s_perm[p]=(unsigned short)tid; }
  }
  __syncthreads();

  const int cnts[3] = {512, 410, 328};   // static alive counts
  const int kks[2]  = {410, 328};        // ceil(0.8*512), ceil(0.8*410)

  for (int l=0; l<3; ++l){
    const float* Wl = gnn_w + (size_t)l*NREL*256;
    // ---- A: Wq/Wk precompute (logit is bilinear) + zero pool cells
    {
      const float4* q4=(const float4*)(gnn_q+l*16);
      const float4* k4=(const float4*)(gnn_k+l*16);
      float4 q0=q4[0],q1=q4[1],q2=q4[2],q3=q4[3];
      float4 c0=k4[0],c1=k4[1],c2=k4[2],c3=k4[3];
      for (int i=tid;i<NREL*16;i+=1024){
        const float4* wr=(const float4*)(Wl+(size_t)i*16);
        float4 a0=wr[0],a1=wr[1],a2=wr[2],a3=wr[3];
        s_wq[(i>>4)*XS+(i&15)] = dot4f(a0,q0)+dot4f(a1,q1)+dot4f(a2,q2)+dot4f(a3,q3);
        s_wk[(i>>4)*XS+(i&15)] = dot4f(a0,c0)+dot4f(a1,c1)+dot4f(a2,c2)+dot4f(a3,c3);
      }
      if (tid<16){ s_sum[tid]=0.f; s_max16[tid]=0u; }
    }
    __syncthreads();
    // ---- PM: per-node merged logit/softmax/aggregate/norm/pool/score
    float rnorm=0.f; float pw4[4]={0,0,0,0};
    if (l<2){
      float ss=0.f;
      #pragma unroll
      for (int o=0;o<16;o++){ float p=pool_w[l*16+o]; ss+=p*p; }
      rnorm = rsqrtf(ss);
      #pragma unroll
      for (int j=0;j<4;j++) pw4[j]=pool_w[l*16+4*og+j];
    }
    const float* bb = gnn_b + l*16;
    const int nA = s_perm[grp], nB = s_perm[511-grp];
    float zA[4], zB[4];
    auto pm_round = [&](int n, float* z){
      int beg = s_off[n], end = s_off[n+1];
      int alive = s_mask[n];
      float2 xt0 = *(const float2*)&s_x[n*XS+4*og];
      float2 xt1 = *(const float2*)&s_x[n*XS+4*og+2];
      // fused sweep: logits + online softmax + W-gather accumulate, 2-edge
      // unroll, epk pair software-pipelined (prefetched one iter ahead)
      float m = -1e30f;
      float den=0.f, v0=0.f, v1=0.f, v2=0.f, v3=0.f;
      int p = beg;
      unsigned pkA = 0u, pkB = 0u;
      if (p+2 <= end){ pkA = s_epk[p]; pkB = s_epk[p+1]; }
      for (; p+2 <= end; p += 2){
        unsigned pk0 = pkA, pk1 = pkB;
        pkA = s_epk[p+2]; pkB = s_epk[p+3];   // prefetch next iter (padded)
        int s0 = pk0 & 0xFFFF, r0 = pk0 >> 16;
        int s1 = pk1 & 0xFFFF, r1 = pk1 >> 16;
        // logits (4-way split dot + 2 shfl each)
        float2 wq00=*(const float2*)&s_wq[r0*XS+4*og];
        float2 wq01=*(const float2*)&s_wq[r0*XS+4*og+2];
        float2 wk00=*(const float2*)&s_wk[r0*XS+4*og];
        float2 wk01=*(const float2*)&s_wk[r0*XS+4*og+2];
        float2 xs00=*(const float2*)&s_x[s0*XS+4*og];
        float2 xs01=*(const float2*)&s_x[s0*XS+4*og+2];
        float a0 = xt0.x*wq00.x + xt0.y*wq00.y + xt1.x*wq01.x + xt1.y*wq01.y
                 + xs00.x*wk00.x + xs00.y*wk00.y + xs01.x*wk01.x + xs01.y*wk01.y;
        float2 wq10=*(const float2*)&s_wq[r1*XS+4*og];
        float2 wq11=*(const float2*)&s_wq[r1*XS+4*og+2];
        float2 wk10=*(const float2*)&s_wk[r1*XS+4*og];
        float2 wk11=*(const float2*)&s_wk[r1*XS+4*og+2];
        float2 xs10=*(const float2*)&s_x[s1*XS+4*og];
        float2 xs11=*(const float2*)&s_x[s1*XS+4*og+2];
        float a1 = xt0.x*wq10.x + xt0.y*wq10.y + xt1.x*wq11.x + xt1.y*wq11.y
                 + xs10.x*wk10.x + xs10.y*wk10.y + xs11.x*wk11.x + xs11.y*wk11.y;
        a0 += __shfl_xor(a0,1); a0 += __shfl_xor(a0,2);
        a1 += __shfl_xor(a1,1); a1 += __shfl_xor(a1,2);
        float lg0 = a0>0.f ? a0 : 0.2f*a0;   // leaky_relu 0.2
        float lg1 = a1>0.f ? a1 : 0.2f*a1;
        // W gather (independent load chains, overlap the logit shfl chain)
        const float4* wr0 = (const float4*)(Wl + (size_t)r0*256) + og;
        const float4* wr1 = (const float4*)(Wl + (size_t)r1*256) + og;
        const float* xr0 = &s_x[s0*XS];
        const float* xr1 = &s_x[s1*XS];
        float h00=0.f,h01=0.f,h02=0.f,h03=0.f;
        float h10=0.f,h11=0.f,h12=0.f,h13=0.f;
        #pragma unroll
        for (int d2=0; d2<8; ++d2){
          float2 xa = *(const float2*)&xr0[2*d2];
          float2 xb = *(const float2*)&xr1[2*d2];
          float4 wA0 = wr0[(2*d2)*4], wB0 = wr0[(2*d2+1)*4];
          float4 wA1 = wr1[(2*d2)*4], wB1 = wr1[(2*d2+1)*4];
          h00 += xa.x*wA0.x + xa.y*wB0.x;  h01 += xa.x*wA0.y + xa.y*wB0.y;
          h02 += xa.x*wA0.z + xa.y*wB0.z;  h03 += xa.x*wA0.w + xa.y*wB0.w;
          h10 += xb.x*wA1.x + xb.y*wB1.x;  h11 += xb.x*wA1.y + xb.y*wB1.y;
          h12 += xb.x*wA1.z + xb.y*wB1.z;  h13 += xb.x*wA1.w + xb.y*wB1.w;
        }
        // online softmax update
        float nm = fmaxf(m, fmaxf(lg0, lg1));
        float sc = __expf(m - nm);             // m=-1e30 first iter -> sc=0
        float e0 = __expf(lg0 - nm);
        float e1 = __expf(lg1 - nm);
        den = den*sc + e0 + e1;
        v0 = v0*sc + e0*h00 + e1*h10;
        v1 = v1*sc + e0*h01 + e1*h11;
        v2 = v2*sc + e0*h02 + e1*h12;
        v3 = v3*sc + e0*h03 + e1*h13;
        m = nm;
      }
      if (p < end){
        unsigned pk = s_epk[p];
        int s = pk & 0xFFFF, r = pk >> 16;
        float2 wq0=*(const float2*)&s_wq[r*XS+4*og];
        float2 wq1=*(const float2*)&s_wq[r*XS+4*og+2];
        float2 wk0=*(const float2*)&s_wk[r*XS+4*og];
        float2 wk1=*(const float2*)&s_wk[r*XS+4*og+2];
        float2 xs0=*(const float2*)&s_x[s*XS+4*og];
        float2 xs1=*(const float2*)&s_x[s*XS+4*og+2];
        float a = xt0.x*wq0.x + xt0.y*wq0.y + xt1.x*wq1.x + xt1.y*wq1.y
                + xs0.x*wk0.x + xs0.y*wk0.y + xs1.x*wk1.x + xs1.y*wk1.y;
        a += __shfl_xor(a,1); a += __shfl_xor(a,2);
        float lg = a>0.f ? a : 0.2f*a;
        const float4* wr = (const float4*)(Wl + (size_t)r*256) + og;
        const float* xr = &s_x[s*XS];
        float h0=0.f,h1=0.f,h2=0.f,h3=0.f;
        #pragma unroll
        for (int d2=0; d2<8; ++d2){
          float2 xs2 = *(const float2*)&xr[2*d2];
          float4 wA = wr[(2*d2)*4];
          float4 wB = wr[(2*d2+1)*4];
          h0 += xs2.x*wA.x + xs2.y*wB.x;
          h1 += xs2.x*wA.y + xs2.y*wB.y;
          h2 += xs2.x*wA.z + xs2.y*wB.z;
          h3 += xs2.x*wA.w + xs2.y*wB.w;
        }
        float nm = fmaxf(m, lg);
        float sc = __expf(m - nm);
        float ex = __expf(lg - nm);
        den = den*sc + ex;
        v0 = v0*sc + ex*h0;
        v1 = v1*sc + ex*h1;
        v2 = v2*sc + ex*h2;
        v3 = v3*sc + ex*h3;
        m = nm;
      }
      float inv = den>0.f ? 1.f/den : 1.f;   // ref: where(den>0, den, 1)
      z[0]=v0*inv+bb[4*og+0]; z[1]=v1*inv+bb[4*og+1];
      z[2]=v2*inv+bb[4*og+2]; z[3]=v3*inv+bb[4*og+3];
      #pragma unroll
      for (int j=0;j<4;j++){ if (z[j]<0.f) z[j]=0.f; }
      if (!alive){ z[0]=z[1]=z[2]=z[3]=0.f; }
      // pool partials: reduce across the wave's 16 node-groups (4-hop shfl)
      #pragma unroll
      for (int j=0;j<4;j++){
        float sv=z[j], mv=z[j];
        #pragma unroll
        for (int off=4; off<64; off<<=1){
          sv += __shfl_xor(sv, off);
          mv = fmaxf(mv, __shfl_xor(mv, off));
        }
        if ((lane>>2)==0){
          atomicAdd(&s_sum[4*og+j], sv);
          atomicMax(&s_max16[4*og+j], __float_as_uint(mv));
        }
      }
      if (l<2){
        float dq = z[0]*pw4[0]+z[1]*pw4[1]+z[2]*pw4[2]+z[3]*pw4[3];
        dq += __shfl_xor(dq,1); dq += __shfl_xor(dq,2);
        if (og==0){
          float sc2 = tanhf(dq*rnorm);
          s_keys[n] = alive ? fkey(sc2) : 0u;   // dead -> 0; alive keys > 0
        }
      }
    };
    pm_round(nA, zA);
    pm_round(nB, zB);
    __syncthreads();
    if (tid<16){
      s_feats[l*32+tid]    = s_sum[tid]/(float)cnts[l];
      s_feats[l*32+16+tid] = __uint_as_float(s_max16[tid]);
    }
    if (l==2) break;
    // ---- z writeback (deferred past barrier: WAR vs fused-sweep x_s reads)
    {
      *(float2*)&s_x[nA*XS+4*og]   = make_float2(zA[0],zA[1]);
      *(float2*)&s_x[nA*XS+4*og+2] = make_float2(zA[2],zA[3]);
      *(float2*)&s_x[nB*XS+4*og]   = make_float2(zB[0],zB[1]);
      *(float2*)&s_x[nB*XS+4*og+2] = make_float2(zB[2],zB[3]);
    }
    __syncthreads();
    // ---- top-k: register-resident wave-redundant bitwise search
    {
      const int kk = kks[l];
      unsigned kreg[8];
      #pragma unroll
      for (int j=0;j<8;j++) kreg[j] = s_keys[lane + j*64];
      unsigned cur = 0u;
      for (int bit=31; bit>=0; --bit){
        unsigned cand = cur | (1u<<bit);
        int c=0;
        #pragma unroll
        for (int j=0;j<8;j++) c += __popcll(__ballot(kreg[j]>=cand));
        if (c >= kk) cur = cand;
      }
      int cgt=0;
      #pragma unroll
      for (int j=0;j<8;j++) cgt += __popcll(__ballot(kreg[j]>cur));
      int ties = kk - cgt;
      // rank among equals by node index (jax top_k lowest-index tie-break)
      unsigned myk = (tid<NPG) ? s_keys[tid] : 0u;
      bool eq = (tid<NPG) && (myk==cur);
      unsigned long long bal = __ballot(eq);
      int lrank = __popcll(bal & ((1ull<<lane)-1ull));
      if (lane==0) s_w[wv] = __popcll(bal);
      __syncthreads();
      int pre=0;
      #pragma unroll
      for (int w=0; w<16; ++w) if (w<wv) pre += s_w[w];
      int rank = pre + lrank;
      if (tid < NPG){
        bool keep = (myk > cur) || (eq && rank < ties);
        float mult = keep ? fdec(myk) : 0.f;   // exact tanh-score roundtrip
        #pragma unroll
        for (int c=0;c<8;c++){
          float2 t2 = *(const float2*)&s_x[tid*XS+2*c];
          t2.x *= mult; t2.y *= mult;
          *(float2*)&s_x[tid*XS+2*c] = t2;
        }
        s_mask[tid] = keep ? 1 : 0;
      }
    }
    __syncthreads();
    // ---- compact surviving edges (re-bin by dst) + rebuild degree perm
    {
      int ne = s_off[NPG];
      unsigned pk0=0, pk1=0; unsigned short dd0=0, dd1=0; bool k0=false, k1=false;
      if (tid < ne){
        pk0 = s_epk[tid]; dd0 = s_edst[tid];
        k0 = s_mask[pk0 & 0xFFFF] && s_mask[dd0];
      }
      if (tid+1024 < ne){
        pk1 = s_epk[tid+1024]; dd1 = s_edst[tid+1024];
        k1 = s_mask[pk1 & 0xFFFF] && s_mask[dd1];
      }
      __syncthreads();
      for (int i=tid;i<NPG;i+=1024) s_hist[i]=0;
      if (tid<64) s_dh[tid]=0;
      __syncthreads();
      if (k0) atomicAdd(&s_hist[dd0], 1);
      if (k1) atomicAdd(&s_hist[dd1], 1);
      __syncthreads();
      scan512(s_hist, s_off, s_wt, tid);
      __syncthreads();
      if (k0){ int p=atomicAdd(&s_hist[dd0],1); s_epk[p]=pk0; s_edst[p]=dd0; }
      if (k1){ int p=atomicAdd(&s_hist[dd1],1); s_epk[p]=pk1; s_edst[p]=dd1; }
      int mydeg=0;
      if (tid<NPG){
        mydeg = s_off[tid+1]-s_off[tid]; if (mydeg>63) mydeg=63;
        atomicAdd(&s_dh[mydeg], 1);
      }
      __syncthreads();
      if (tid<64){
        int c = s_dh[tid], inc = c;
        #pragma unroll
        for (int o=1;o<64;o<<=1){ int t=__shfl_up(inc,o); if (tid>=o) inc+=t; }
        s_dh[tid] = inc - c;
      }
      __syncthreads();
      if (tid<NPG){ int p = atomicAdd(&s_dh[mydeg],1); s_perm[p]=(unsigned short)tid; }
      __syncthreads();
    }
  }

  // ---- MLP head (feats never leave LDS)
  __syncthreads();
  if (tid < 16){
    float a = b1[tid];
    for (int i=0;i<96;i++) a += s_feats[i]*w1[i*16+tid];
    s_h1[tid] = a>0.f?a:0.f;
  }
  __syncthreads();
  if (tid < 4){
    float a = b2[tid];
    #pragma unroll
    for (int i=0;i<16;i++) a += s_h1[i]*w2[i*4+tid];
    s_h2[tid] = a>0.f?a:0.f;
  }
  __syncthreads();
  if (tid == 0){
    float z = b3[0];
    #pragma unroll
    for (int i=0;i<4;i++) z += s_h2[i]*w3[i];
    out[b] = 1.f/(1.f+expf(-z));
  }
}

extern "C" void kernel_launch(void* const* d_in, const int* in_sizes, int n_in,
                              void* d_out, int out_size, void* d_ws, size_t ws_size,
                              hipStream_t stream) {
  const float* emb    = (const float*)d_in[0];
  const float* gnn_w  = (const float*)d_in[1];
  const float* gnn_q  = (const float*)d_in[2];
  const float* gnn_k  = (const float*)d_in[3];
  const float* gnn_b  = (const float*)d_in[4];
  const float* pool_w = (const float*)d_in[5];
  const float* w1 = (const float*)d_in[6];
  const float* b1 = (const float*)d_in[7];
  const float* w2 = (const float*)d_in[8];
  const float* b2 = (const float*)d_in[9];
  const float* w3 = (const float*)d_in[10];
  const float* b3 = (const float*)d_in[11];
  const int* xattr = (const int*)d_in[12];
  const int* eidx  = (const int*)d_in[13];
  const int* etype = (const int*)d_in[14];
  const int* src = eidx;
  const int* dst = eidx + (size_t)B_*EPG;

  k_fused<<<B_, 1024, 0, stream>>>(emb, gnn_w, gnn_q, gnn_k, gnn_b, pool_w,
                                   w1, b1, w2, b2, w3, b3,
                                   xattr, src, dst, etype, (float*)d_out);
}